// Round 17
// baseline (2556.437 us; speedup 1.0000x reference)
//
#include <hip/hip_runtime.h>

#define NPTS    2048
#define NBATCH  8
#define NPROB   24     // 8 batches x {xy, xx, yy}
#define NITER   30
#define TPB     512
#define WPB     8      // waves per block
#define NJOBS   32     // 16 row-chunks (128 rows) x 2 col-halves
#define HCOLS   1024   // columns per half
#define NTIL    16     // tiles of 64 cols per half
#define MARGIN  28.0f  // log2 safety margin for tile truncation

// eps = 0.05, log-domain Sinkhorn in log2 space.
constexpr float KSC  = 28.853900817779268f;   // log2(e)/eps
constexpr float INVK = 0.034657359027997264f; // 1/KSC
constexpr float C1f  = 0.38123094930796995f;  // eps*ln(2048)
constexpr float C2f  = 0.03465735902799726f;  // eps*ln(2)
// Exact identities: KSC*C1f = log2(2048) = 11, KSC*C2f = 1

typedef float v2f __attribute__((ext_vector_type(2)));   // row0 = .x, row1 = .y

__device__ __forceinline__ float fexp2(float x) { return __builtin_amdgcn_exp2f(x); }
__device__ __forceinline__ float flog2(float x) { return __builtin_amdgcn_logf(x); }
__device__ __forceinline__ float fsqrt(float x) { return __builtin_amdgcn_sqrtf(x); }

// ---------- prep: Morton sort each side, write permuted coords + tile bboxes ----------
__device__ __forceinline__ unsigned long long mspread(unsigned v) {
    unsigned long long x = v & 1023ull;
    x = (x | (x << 16)) & 0x030000FFull;
    x = (x | (x << 8))  & 0x0300F00Full;
    x = (x | (x << 4))  & 0x030C30C3ull;
    x = (x | (x << 2))  & 0x09249249ull;
    return x;
}
__device__ __forceinline__ unsigned q10(float v) {
    int q = (int)((v + 8.0f) * 64.0f);           // [-8,8) -> [0,1024)
    return (unsigned)(q < 0 ? 0 : (q > 1023 ? 1023 : q));
}

__global__ __launch_bounds__(TPB)
void prep_sort(const float* __restrict__ xyz1, const float* __restrict__ xyz2,
               float* __restrict__ pc, float* __restrict__ bbox)
{
    __shared__ unsigned long long keys[NPTS];    // (morton<<11) | idx  (16 KB)
    const int s  = blockIdx.x;                   // side: 2b = x of batch b, 2b+1 = y
    const int b  = s >> 1;
    const float* src = (s & 1) ? (xyz2 + (size_t)b * NPTS * 3)
                               : (xyz1 + (size_t)b * NPTS * 3);
    const int tid = threadIdx.x;

    for (int i = tid; i < NPTS; i += TPB) {
        float x = src[3*i], y = src[3*i+1], z = src[3*i+2];
        unsigned long long code = (mspread(q10(x)) << 2) |
                                  (mspread(q10(y)) << 1) |
                                   mspread(q10(z));
        keys[i] = (code << 11) | (unsigned long long)i;
    }
    __syncthreads();

    for (int k = 2; k <= NPTS; k <<= 1) {
        for (int j = k >> 1; j > 0; j >>= 1) {
            for (int t = tid; t < NPTS / 2; t += TPB) {
                const int lo = t & (j - 1);
                const int i  = ((t - lo) << 1) + lo;
                const int ix = i + j;
                const bool asc = ((i & k) == 0);
                unsigned long long a = keys[i], c = keys[ix];
                if ((a > c) == asc) { keys[i] = c; keys[ix] = a; }
            }
            __syncthreads();
        }
    }

    float* dst = pc + (size_t)s * NPTS * 3;
    for (int i = tid; i < NPTS; i += TPB) {
        const int pi = (int)(keys[i] & 2047ull);
        dst[3*i+0] = src[3*pi+0];
        dst[3*i+1] = src[3*pi+1];
        dst[3*i+2] = src[3*pi+2];
    }

    if (tid < 32) {
        float lox = 1e30f, loy = 1e30f, loz = 1e30f;
        float hix = -1e30f, hiy = -1e30f, hiz = -1e30f;
        for (int q = 0; q < 64; ++q) {
            const int pi = (int)(keys[tid * 64 + q] & 2047ull);
            const float x = src[3*pi], y = src[3*pi+1], z = src[3*pi+2];
            lox = fminf(lox, x); hix = fmaxf(hix, x);
            loy = fminf(loy, y); hiy = fmaxf(hiy, y);
            loz = fminf(loz, z); hiz = fmaxf(hiz, z);
        }
        float* bb = bbox + ((size_t)s * 32 + tid) * 8;
        bb[0] = lox; bb[1] = loy; bb[2] = loz; bb[3] = hix;
        bb[4] = hiy; bb[5] = hiz; bb[6] = 0.f; bb[7] = 0.f;
    }
}

__global__ __launch_bounds__(256)
void init_sums(float* __restrict__ gsum)
{
    int i = blockIdx.x * 256 + threadIdx.x;
    if (i < NPROB * 2 * NPTS) gsum[i] = 1024.0f;   // halves sum to 2048 -> K*phi0 = 0
}

__device__ __forceinline__ void problem_barrier(unsigned* arrive, unsigned* epoch,
                                                unsigned phase, int nbpp, int tid)
{
    __syncthreads();
    if (tid == 0) {
        unsigned old = __hip_atomic_fetch_add(arrive, 1u, __ATOMIC_ACQ_REL,
                                              __HIP_MEMORY_SCOPE_AGENT);
        if (old == (unsigned)(nbpp - 1)) {
            __hip_atomic_store(arrive, 0u, __ATOMIC_RELAXED, __HIP_MEMORY_SCOPE_AGENT);
            __hip_atomic_store(epoch, phase, __ATOMIC_RELEASE, __HIP_MEMORY_SCOPE_AGENT);
        } else {
            while (__hip_atomic_load(epoch, __ATOMIC_RELAXED,
                                     __HIP_MEMORY_SCOPE_AGENT) < phase) {
                __builtin_amdgcn_s_sleep(2);
            }
            __threadfence();
        }
    }
    __syncthreads();
}

__global__ __launch_bounds__(TPB, 6)
void sinkhorn_all(const float* __restrict__ pc,   // permuted coords, 16 sides
                  const float* __restrict__ bbox, // [16 sides][32 tiles][8]
                  float* __restrict__ fsum,       // [NPROB][2][NPTS] raw partial sums
                  float* __restrict__ gsum,
                  unsigned* __restrict__ bars,
                  int nbpp)
{
    __shared__ float4 shC[2][HCOLS];       // 32 KB: {x,y,z,K*phi} per column side
    __shared__ float  shS[WPB][128];       // 4 KB: per-wave partials (2 rows/lane)
    __shared__ float4 shB[2][NTIL][2];     // 512B: tile bbox {lox,loy,loz,hix},{hiy,hiz,-,-}
    __shared__ float  shTmax[NTIL];        // per-tile max of staged w (current pass)
    __shared__ float  shTmin[NTIL];

    const int tid  = threadIdx.x;
    const int lane = tid & 63;
    const int warp = tid >> 6;
    const int p    = blockIdx.x % NPROB;
    const int lb   = blockIdx.x / NPROB;
    const int b    = p / 3;
    const int k    = p - 3 * b;            // 0: xy, 1: xx, 2: yy

    const float* xb = pc + (size_t)(2 * b) * NPTS * 3;
    const float* yb = pc + (size_t)(2 * b + 1) * NPTS * 3;
    float* fS = fsum + (size_t)p * 2 * NPTS;
    float* gS = gsum + (size_t)p * 2 * NPTS;
    unsigned* arrive = bars + (size_t)p * 64;
    unsigned* epoch  = bars + (size_t)p * 64 + 32;

    const float* Uf = (k == 2) ? yb : xb;
    const float* Ug = (k == 0) ? yb : ((k == 1) ? xb : yb);
    const float* Vf = (k == 1) ? xb : yb;
    const float* Vg = (k == 2) ? yb : xb;
    const int sideG = (Vg == Vf) ? 0 : 1;
    const int sVf   = 2 * b + ((k == 1) ? 0 : 1);   // bbox side of Vf
    const int sVg   = 2 * b + ((k == 2) ? 1 : 0);   // bbox side of Vg

    auto stage_coords = [&](const float* __restrict__ V, int side, int h) {
        if (tid < 256) {
            const float4* V4 = (const float4*)V;
            const int i0 = 3 * (h * 256 + tid);
            const float4 a  = V4[i0 + 0];
            const float4 bb = V4[i0 + 1];
            const float4 cc = V4[i0 + 2];
            const int c = 4 * tid;
            shC[side][c + 0] = make_float4(a.x,  a.y,  a.z,  0.f);
            shC[side][c + 1] = make_float4(a.w,  bb.x, bb.y, 0.f);
            shC[side][c + 2] = make_float4(bb.z, bb.w, cc.x, 0.f);
            shC[side][c + 3] = make_float4(cc.y, cc.z, cc.w, 0.f);
        }
    };
    // per-pass w-refresh + per-tile w stats (32-lane shfl reduce, tile = 64 cols)
    auto stage_w = [&](const float* __restrict__ S, int side, int h) {
        const int c  = 2 * tid;
        const int gc = h * HCOLS + c;
        const float2 t0 = *(const float2*)(S + gc);
        const float2 t1 = *(const float2*)(S + NPTS + gc);
        const float w0 = 11.0f - flog2(t0.x + t1.x);
        const float w1 = 11.0f - flog2(t0.y + t1.y);
        shC[side][c + 0].w = w0;
        shC[side][c + 1].w = w1;
        float wmx = fmaxf(w0, w1), wmn = fminf(w0, w1);
        #pragma unroll
        for (int m = 1; m < 32; m <<= 1) {
            wmx = fmaxf(wmx, __shfl_xor(wmx, m));
            wmn = fminf(wmn, __shfl_xor(wmn, m));
        }
        if ((tid & 31) == 0) {               // tile = tid>>5 (2 cols/thread, 64/tile)
            shTmax[tid >> 5] = wmx;
            shTmin[tid >> 5] = wmn;
        }
    };
    auto stage_full = [&](const float* __restrict__ V, const float* __restrict__ S,
                          int side, int h) {
        if (tid < 256) {
            const float4* V4 = (const float4*)V;
            const int i0 = 3 * (h * 256 + tid);
            const float4 a  = V4[i0 + 0];
            const float4 bb = V4[i0 + 1];
            const float4 cc = V4[i0 + 2];
            const int c  = 4 * tid;
            const int gc = h * HCOLS + c;
            const float4 t0 = *(const float4*)(S + gc);
            const float4 t1 = *(const float4*)(S + NPTS + gc);
            shC[side][c + 0] = make_float4(a.x,  a.y,  a.z,  11.0f - flog2(t0.x + t1.x));
            shC[side][c + 1] = make_float4(a.w,  bb.x, bb.y, 11.0f - flog2(t0.y + t1.y));
            shC[side][c + 2] = make_float4(bb.z, bb.w, cc.x, 11.0f - flog2(t0.z + t1.z));
            shC[side][c + 3] = make_float4(cc.y, cc.z, cc.w, 11.0f - flog2(t0.w + t1.w));
        }
    };

    // one job: 128 rows (2/lane, packed fp32) x 1024 cols, tile-truncated
    auto do_pass = [&](const float* __restrict__ U, float* __restrict__ oS,
                       int side, int h, int rc, bool trunc) {
        __syncthreads();                    // staging + stats visible
        const int r0 = rc * 128 + lane, r1 = r0 + 64;
        const v2f ux = {U[3*r0],   U[3*r1]};
        const v2f uy = {U[3*r0+1], U[3*r1+1]};
        const v2f uz = {U[3*r0+2], U[3*r1+2]};
        const v2f e12 = {1e-12f, 1e-12f};
        const v2f nK  = {-KSC, -KSC};
        v2f s0 = {0.f, 0.f}, s1 = {0.f, 0.f}, s2 = {0.f, 0.f}, s3 = {0.f, 0.f};

        unsigned mask = 0xFFFFu;
        if (trunc) {
            // Phase A: LB_row = max_t (wmin_t - K*dmax(row, tile_t))  [rigorous]
            float LB0 = -3.0e38f, LB1 = -3.0e38f;
            #pragma unroll 4
            for (int t = 0; t < NTIL; ++t) {
                const float4 A = shB[side][t][0];   // lox,loy,loz,hix
                const float4 B = shB[side][t][1];   // hiy,hiz,-,-
                const float wmn = shTmin[t];
                {
                    const float ex = fmaxf(ux.x - A.x, A.w - ux.x);
                    const float ey = fmaxf(uy.x - A.y, B.x - uy.x);
                    const float ez = fmaxf(uz.x - A.z, B.y - uz.x);
                    const float dmx = fsqrt(fmaf(ex, ex, fmaf(ey, ey, ez * ez)));
                    LB0 = fmaxf(LB0, fmaf(-KSC, dmx, wmn));
                }
                {
                    const float ex = fmaxf(ux.y - A.x, A.w - ux.y);
                    const float ey = fmaxf(uy.y - A.y, B.x - uy.y);
                    const float ez = fmaxf(uz.y - A.z, B.y - uz.y);
                    const float dmx = fsqrt(fmaf(ex, ex, fmaf(ey, ey, ez * ez)));
                    LB1 = fmaxf(LB1, fmaf(-KSC, dmx, wmn));
                }
            }
            // Phase B: skip tile iff wmax_t - K*dmin < LB - MARGIN for both rows, all lanes
            mask = 0;
            #pragma unroll 4
            for (int t = 0; t < NTIL; ++t) {
                const float4 A = shB[side][t][0];
                const float4 B = shB[side][t][1];
                const float wmx = shTmax[t];
                bool sk0, sk1;
                {
                    const float ex = fmaxf(fmaxf(A.x - ux.x, ux.x - A.w), 0.f);
                    const float ey = fmaxf(fmaxf(A.y - uy.x, uy.x - B.x), 0.f);
                    const float ez = fmaxf(fmaxf(A.z - uz.x, uz.x - B.y), 0.f);
                    const float dmin2 = fmaf(ex, ex, fmaf(ey, ey, ez * ez));
                    const float rhs = fmaxf(wmx - LB0 + MARGIN, 0.f) * INVK;
                    sk0 = dmin2 > rhs * rhs;
                }
                {
                    const float ex = fmaxf(fmaxf(A.x - ux.y, ux.y - A.w), 0.f);
                    const float ey = fmaxf(fmaxf(A.y - uy.y, uy.y - B.x), 0.f);
                    const float ez = fmaxf(fmaxf(A.z - uz.y, uz.y - B.y), 0.f);
                    const float dmin2 = fmaf(ex, ex, fmaf(ey, ey, ez * ez));
                    const float rhs = fmaxf(wmx - LB1 + MARGIN, 0.f) * INVK;
                    sk1 = dmin2 > rhs * rhs;
                }
                if (__any(!(sk0 && sk1))) mask |= (1u << t);
            }
        }

        auto term = [&](const float4 v) -> v2f {
            v2f dx = ux - (v2f){v.x, v.x};
            v2f dy = uy - (v2f){v.y, v.y};
            v2f dz = uz - (v2f){v.z, v.z};
            v2f d2 = __builtin_elementwise_fma(dz, dz, e12);
            d2 = __builtin_elementwise_fma(dy, dy, d2);
            d2 = __builtin_elementwise_fma(dx, dx, d2);
            v2f sq  = {fsqrt(d2.x), fsqrt(d2.y)};
            v2f arg = __builtin_elementwise_fma(nK, sq, (v2f){v.w, v.w});
            return (v2f){fexp2(arg.x), fexp2(arg.y)};
        };
        const int cbase = warp * 4;
        for (int t = 0; t < NTIL; ++t) {
            if (!((mask >> t) & 1u)) continue;       // wave-uniform branch
            const int cA = 64 * t + cbase;           // group 2t
            {
                const float4 v0 = shC[side][cA + 0];
                const float4 v1 = shC[side][cA + 1];
                const float4 v2 = shC[side][cA + 2];
                const float4 v3 = shC[side][cA + 3];
                s0 += term(v0); s1 += term(v1); s2 += term(v2); s3 += term(v3);
            }
            {
                const int cB = cA + 32;              // group 2t+1
                const float4 v0 = shC[side][cB + 0];
                const float4 v1 = shC[side][cB + 1];
                const float4 v2 = shC[side][cB + 2];
                const float4 v3 = shC[side][cB + 3];
                s0 += term(v0); s1 += term(v1); s2 += term(v2); s3 += term(v3);
            }
        }
        shS[warp][lane]      = (s0.x + s1.x) + (s2.x + s3.x);
        shS[warp][lane + 64] = (s0.y + s1.y) + (s2.y + s3.y);
        __syncthreads();
        if (tid < 128) {
            float t = shS[0][tid];
            #pragma unroll
            for (int w = 1; w < WPB; ++w) t += shS[w][tid];
            oS[h * NPTS + rc * 128 + tid] = t;
        }
        __syncthreads();
    };

    if (nbpp == NJOBS) {
        const int h  = lb & 1;
        const int rc = lb >> 1;
        stage_coords(Vf, 0, h);
        if (sideG == 1) stage_coords(Vg, 1, h);
        // stage tile bboxes for this half ONCE (side 0 = Vf, side 1 = Vg)
        if (tid < NTIL) {
            const float* bb = bbox + ((size_t)sVf * 32 + h * NTIL + tid) * 8;
            shB[0][tid][0] = make_float4(bb[0], bb[1], bb[2], bb[3]);
            shB[0][tid][1] = make_float4(bb[4], bb[5], 0.f, 0.f);
        } else if (tid < 2 * NTIL) {
            const int t = tid - NTIL;
            const float* bb = bbox + ((size_t)sVg * 32 + h * NTIL + t) * 8;
            shB[1][t][0] = make_float4(bb[0], bb[1], bb[2], bb[3]);
            shB[1][t][1] = make_float4(bb[4], bb[5], 0.f, 0.f);
        }

        for (int it = 0; it < NITER; ++it) {
            stage_w(gS, 0, h);
            do_pass(Uf, fS, 0, h, rc, true);
            problem_barrier(arrive, epoch, (unsigned)(2 * it + 1), nbpp, tid);
            stage_w(fS, sideG, h);
            do_pass(Ug, gS, sideG, h, rc, true);
            problem_barrier(arrive, epoch, (unsigned)(2 * it + 2), nbpp, tid);
        }
    } else {
        for (int it = 0; it < NITER; ++it) {
            for (int j = lb; j < NJOBS; j += nbpp) {
                stage_full(Vf, gS, 0, j & 1);
                do_pass(Uf, fS, 0, j & 1, j >> 1, false);
            }
            problem_barrier(arrive, epoch, (unsigned)(2 * it + 1), nbpp, tid);
            for (int j = lb; j < NJOBS; j += nbpp) {
                stage_full(Vg, fS, 0, j & 1);
                do_pass(Ug, gS, 0, j & 1, j >> 1, false);
            }
            problem_barrier(arrive, epoch, (unsigned)(2 * it + 2), nbpp, tid);
        }
    }
}

__global__ __launch_bounds__(TPB, 1)
void final_reduce(const float* __restrict__ fsum, const float* __restrict__ gsum,
                  float* __restrict__ out)
{
    __shared__ double red[WPB];
    const int tid  = threadIdx.x;
    const int lane = tid & 63;
    const int warp = tid >> 6;

    double acc = 0.0;
    for (int idx = tid; idx < 2 * NPROB * NPTS; idx += TPB) {
        const bool isF = idx < NPROB * NPTS;
        const int rem  = isF ? idx : idx - NPROB * NPTS;
        const int pp   = rem >> 11;
        const int j    = rem & (NPTS - 1);
        const float* S = (isF ? fsum : gsum) + (size_t)pp * 2 * NPTS;
        const float t  = S[j] + S[NPTS + j];
        const float val = C1f - C2f * flog2(t);
        const float w   = (pp % 3 == 0) ? 1.0f : -0.5f;
        acc += (double)val * (double)w;
    }
    #pragma unroll
    for (int off = 32; off > 0; off >>= 1) acc += __shfl_xor(acc, off);
    if (lane == 0) red[warp] = acc;
    __syncthreads();
    if (warp == 0) {
        double v2 = (lane < WPB) ? red[lane] : 0.0;
        #pragma unroll
        for (int off = 32; off > 0; off >>= 1) v2 += __shfl_xor(v2, off);
        if (lane == 0) out[0] = (float)(v2 / (double)(NBATCH * NPTS));
    }
}

extern "C" void kernel_launch(void* const* d_in, const int* in_sizes, int n_in,
                              void* d_out, int out_size, void* d_ws, size_t ws_size,
                              hipStream_t stream)
{
    const float* xyz1 = (const float*)d_in[0];
    const float* xyz2 = (const float*)d_in[1];
    float* out = (float*)d_out;

    float* fsum = (float*)d_ws;
    float* gsum = fsum + (size_t)NPROB * 2 * NPTS;
    float* pc   = gsum + (size_t)NPROB * 2 * NPTS;
    float* bbox = pc   + (size_t)16 * NPTS * 3;
    unsigned* bars = (unsigned*)(bbox + (size_t)16 * 32 * 8);

    hipMemsetAsync(bars, 0, (size_t)NPROB * 64 * sizeof(unsigned), stream);
    prep_sort<<<16, TPB, 0, stream>>>(xyz1, xyz2, pc, bbox);
    init_sums<<<(NPROB * 2 * NPTS + 255) / 256, 256, 0, stream>>>(gsum);

    int maxB = 0;
    hipOccupancyMaxActiveBlocksPerMultiprocessor(&maxB, sinkhorn_all, TPB, 0);
    if (maxB < 1) maxB = 1;
    int bpp = (maxB * 256) / NPROB;
    if (bpp > NJOBS) bpp = NJOBS;
    if (bpp < 1) bpp = 1;
    int nblk = NPROB * bpp;

    void* args[] = { (void*)&pc, (void*)&bbox, (void*)&fsum, (void*)&gsum,
                     (void*)&bars, (void*)&bpp };
    hipLaunchCooperativeKernel((void*)sinkhorn_all, dim3(nblk), dim3(TPB),
                               args, 0, stream);

    final_reduce<<<1, TPB, 0, stream>>>(fsum, gsum, out);
}

// Round 18
// 2345.183 us; speedup vs baseline: 1.0901x; 1.0901x over previous
//
#include <hip/hip_runtime.h>

#define NPTS    2048
#define NBATCH  8
#define NPROB   24     // 8 batches x {xy, xx, yy}
#define NITER   30
#define TPB     512
#define WPB     8      // waves per block
#define NJOBS   32     // 16 row-chunks (128 rows) x 2 col-halves
#define HCOLS   1024   // columns per half
#define CPW     128    // columns per wave within a half

// eps = 0.05, log-domain Sinkhorn in log2 space.
constexpr float KSC = 28.853900817779268f;   // log2(e)/eps
constexpr float C1f = 0.38123094930796995f;  // eps*ln(2048)
constexpr float C2f = 0.03465735902799726f;  // eps*ln(2)
// Exact identities: KSC*C1f = log2(2048) = 11, KSC*C2f = 1
//  => staged potential K*phi = 11 - log2(sum_half0 + sum_half1)

typedef float v2f __attribute__((ext_vector_type(2)));   // row0 = .x, row1 = .y

__device__ __forceinline__ float fexp2(float x) { return __builtin_amdgcn_exp2f(x); }
__device__ __forceinline__ float flog2(float x) { return __builtin_amdgcn_logf(x); }
__device__ __forceinline__ float fsqrt(float x) { return __builtin_amdgcn_sqrtf(x); }

__global__ __launch_bounds__(256)
void init_sums(float* __restrict__ gsum)
{
    int i = blockIdx.x * 256 + threadIdx.x;
    if (i < NPROB * 2 * NPTS) gsum[i] = 1024.0f;   // halves sum to 2048 -> K*phi0 = 0
}

__device__ __forceinline__ void problem_barrier(unsigned* arrive, unsigned* epoch,
                                                unsigned phase, int nbpp, int tid)
{
    __syncthreads();   // drain all waves' work before the release RMW
    if (tid == 0) {
        unsigned old = __hip_atomic_fetch_add(arrive, 1u, __ATOMIC_ACQ_REL,
                                              __HIP_MEMORY_SCOPE_AGENT);
        if (old == (unsigned)(nbpp - 1)) {
            __hip_atomic_store(arrive, 0u, __ATOMIC_RELAXED, __HIP_MEMORY_SCOPE_AGENT);
            __hip_atomic_store(epoch, phase, __ATOMIC_RELEASE, __HIP_MEMORY_SCOPE_AGENT);
        } else {
            while (__hip_atomic_load(epoch, __ATOMIC_RELAXED,
                                     __HIP_MEMORY_SCOPE_AGENT) < phase) {
                __builtin_amdgcn_s_sleep(1);     // r18: finer release pickup
            }
            __threadfence();   // acquire: fresh sums visible to this CU
        }
    }
    __syncthreads();
}

__global__ __launch_bounds__(TPB, 6)
void sinkhorn_all(const float* __restrict__ xyz1,
                  const float* __restrict__ xyz2,
                  float* __restrict__ fsum,    // [NPROB][2][NPTS] raw partial sums
                  float* __restrict__ gsum,    // [NPROB][2][NPTS]
                  unsigned* __restrict__ bars,
                  int nbpp)
{
    __shared__ float4 shC[2][HCOLS];    // 32 KB: {x,y,z,K*phi} per column side
    __shared__ float  shS[WPB][128];    // 4 KB: per-wave partials (2 rows/lane)

    const int tid  = threadIdx.x;
    const int lane = tid & 63;
    const int warp = tid >> 6;
    const int p    = blockIdx.x % NPROB;   // blocks of one problem share an XCD (24%8==0)
    const int lb   = blockIdx.x / NPROB;
    const int b    = p / 3;
    const int k    = p - 3 * b;            // 0: xy, 1: xx, 2: yy

    const float* xb = xyz1 + (size_t)b * NPTS * 3;
    const float* yb = xyz2 + (size_t)b * NPTS * 3;
    float* fS = fsum + (size_t)p * 2 * NPTS;
    float* gS = gsum + (size_t)p * 2 * NPTS;
    unsigned* arrive = bars + (size_t)p * 64;
    unsigned* epoch  = bars + (size_t)p * 64 + 32;

    // rows/cols of the f-update and g-update
    const float* Uf = (k == 2) ? yb : xb;
    const float* Ug = (k == 0) ? yb : ((k == 1) ? xb : yb);
    const float* Vf = (k == 1) ? xb : yb;
    const float* Vg = (k == 2) ? yb : xb;
    const int sideG = (Vg == Vf) ? 0 : 1;      // xy: side1 = x; xx/yy: single side

    // coords of col-half h -> shC[side] (w placeholder; refreshed per pass)
    auto stage_coords = [&](const float* __restrict__ V, int side, int h) {
        if (tid < 256) {
            const float4* V4 = (const float4*)V;   // 16B-aligned (24KB batch stride)
            const int i0 = 3 * (h * 256 + tid);
            const float4 a  = V4[i0 + 0];
            const float4 bb = V4[i0 + 1];
            const float4 cc = V4[i0 + 2];
            const int c = 4 * tid;
            shC[side][c + 0] = make_float4(a.x,  a.y,  a.z,  0.f);
            shC[side][c + 1] = make_float4(a.w,  bb.x, bb.y, 0.f);
            shC[side][c + 2] = make_float4(bb.z, bb.w, cc.x, 0.f);
            shC[side][c + 3] = make_float4(cc.y, cc.z, cc.w, 0.f);
        }
    };
    // per-pass stage = w-refresh only (coords persist).
    auto stage_w = [&](const float* __restrict__ S, int side, int h) {
        const int c  = 2 * tid;
        const int gc = h * HCOLS + c;
        const float2 t0 = *(const float2*)(S + gc);
        const float2 t1 = *(const float2*)(S + NPTS + gc);
        shC[side][c + 0].w = 11.0f - flog2(t0.x + t1.x);
        shC[side][c + 1].w = 11.0f - flog2(t0.y + t1.y);
    };
    // fallback (nbpp != 32): full per-job stage
    auto stage_full = [&](const float* __restrict__ V, const float* __restrict__ S,
                          int side, int h) {
        if (tid < 256) {
            const float4* V4 = (const float4*)V;
            const int i0 = 3 * (h * 256 + tid);
            const float4 a  = V4[i0 + 0];
            const float4 bb = V4[i0 + 1];
            const float4 cc = V4[i0 + 2];
            const int c  = 4 * tid;
            const int gc = h * HCOLS + c;
            const float4 t0 = *(const float4*)(S + gc);
            const float4 t1 = *(const float4*)(S + NPTS + gc);
            shC[side][c + 0] = make_float4(a.x,  a.y,  a.z,  11.0f - flog2(t0.x + t1.x));
            shC[side][c + 1] = make_float4(a.w,  bb.x, bb.y, 11.0f - flog2(t0.y + t1.y));
            shC[side][c + 2] = make_float4(bb.z, bb.w, cc.x, 11.0f - flog2(t0.z + t1.z));
            shC[side][c + 3] = make_float4(cc.y, cc.z, cc.w, 11.0f - flog2(t0.w + t1.w));
        }
    };

    // one job: 128 rows (2/lane, packed fp32) x one half's 1024 cols
    auto do_pass = [&](const float* __restrict__ U, float* __restrict__ oS,
                       int side, int h, int rc) {
        __syncthreads();                    // staging visible
        const int r0 = rc * 128 + lane, r1 = r0 + 64;
        const v2f ux = {U[3*r0],   U[3*r1]};
        const v2f uy = {U[3*r0+1], U[3*r1+1]};
        const v2f uz = {U[3*r0+2], U[3*r1+2]};
        const v2f e12 = {1e-12f, 1e-12f};
        const v2f nK  = {-KSC, -KSC};
        v2f s0 = {0.f, 0.f}, s1 = {0.f, 0.f}, s2 = {0.f, 0.f}, s3 = {0.f, 0.f};

        auto term = [&](const float4 v) -> v2f {
            v2f dx = ux - (v2f){v.x, v.x};
            v2f dy = uy - (v2f){v.y, v.y};
            v2f dz = uz - (v2f){v.z, v.z};
            v2f d2 = __builtin_elementwise_fma(dz, dz, e12);
            d2 = __builtin_elementwise_fma(dy, dy, d2);
            d2 = __builtin_elementwise_fma(dx, dx, d2);
            v2f sq  = {fsqrt(d2.x), fsqrt(d2.y)};
            v2f arg = __builtin_elementwise_fma(nK, sq, (v2f){v.w, v.w});
            return (v2f){fexp2(arg.x), fexp2(arg.y)};
        };
        const int cb = warp * CPW;
        #pragma unroll 4                    // r18: deeper trans-chain ILP (was 2)
        for (int c = cb; c < cb + CPW; c += 4) {
            const float4 v0 = shC[side][c + 0];
            const float4 v1 = shC[side][c + 1];
            const float4 v2 = shC[side][c + 2];
            const float4 v3 = shC[side][c + 3];
            s0 += term(v0);
            s1 += term(v1);
            s2 += term(v2);
            s3 += term(v3);
        }
        shS[warp][lane]      = (s0.x + s1.x) + (s2.x + s3.x);
        shS[warp][lane + 64] = (s0.y + s1.y) + (s2.y + s3.y);
        __syncthreads();
        if (tid < 128) {                    // merge 8 col-slices; write raw SUM
            float t = shS[0][tid];
            #pragma unroll
            for (int w = 1; w < WPB; ++w) t += shS[w][tid];
            oS[h * NPTS + rc * 128 + tid] = t;   // coalesced 512B, disjoint per job
        }
        __syncthreads();                    // shC/shS safe for the next stage
    };

    if (nbpp == NJOBS) {
        // fast path: fixed job per block -> coords staged ONCE for both sides
        const int h  = lb & 1;
        const int rc = lb >> 1;
        stage_coords(Vf, 0, h);
        if (sideG == 1) stage_coords(Vg, 1, h);

        for (int it = 0; it < NITER; ++it) {
            stage_w(gS, 0, h);
            do_pass(Uf, fS, 0, h, rc);
            problem_barrier(arrive, epoch, (unsigned)(2 * it + 1), nbpp, tid);
            stage_w(fS, sideG, h);
            do_pass(Ug, gS, sideG, h, rc);
            problem_barrier(arrive, epoch, (unsigned)(2 * it + 2), nbpp, tid);
        }
    } else {
        // robust path (any nbpp): full stage per job
        for (int it = 0; it < NITER; ++it) {
            for (int j = lb; j < NJOBS; j += nbpp) {
                stage_full(Vf, gS, 0, j & 1);
                do_pass(Uf, fS, 0, j & 1, j >> 1);
            }
            problem_barrier(arrive, epoch, (unsigned)(2 * it + 1), nbpp, tid);
            for (int j = lb; j < NJOBS; j += nbpp) {
                stage_full(Vg, fS, 0, j & 1);
                do_pass(Ug, gS, 0, j & 1, j >> 1);
            }
            problem_barrier(arrive, epoch, (unsigned)(2 * it + 2), nbpp, tid);
        }
    }
    // no grid.sync: kernel end is the fence; reduce runs as a separate launch
}

__global__ __launch_bounds__(TPB, 1)
void final_reduce(const float* __restrict__ fsum, const float* __restrict__ gsum,
                  float* __restrict__ out)
{
    __shared__ double red[WPB];
    const int tid  = threadIdx.x;
    const int lane = tid & 63;
    const int warp = tid >> 6;

    double acc = 0.0;
    for (int idx = tid; idx < 2 * NPROB * NPTS; idx += TPB) {
        const bool isF = idx < NPROB * NPTS;
        const int rem  = isF ? idx : idx - NPROB * NPTS;
        const int pp   = rem >> 11;            // / 2048
        const int j    = rem & (NPTS - 1);
        const float* S = (isF ? fsum : gsum) + (size_t)pp * 2 * NPTS;
        const float t  = S[j] + S[NPTS + j];
        const float val = C1f - C2f * flog2(t);
        const float w   = (pp % 3 == 0) ? 1.0f : -0.5f;
        acc += (double)val * (double)w;
    }
    #pragma unroll
    for (int off = 32; off > 0; off >>= 1) acc += __shfl_xor(acc, off);
    if (lane == 0) red[warp] = acc;
    __syncthreads();
    if (warp == 0) {
        double v2 = (lane < WPB) ? red[lane] : 0.0;
        #pragma unroll
        for (int off = 32; off > 0; off >>= 1) v2 += __shfl_xor(v2, off);
        if (lane == 0) out[0] = (float)(v2 / (double)(NBATCH * NPTS));
    }
}

extern "C" void kernel_launch(void* const* d_in, const int* in_sizes, int n_in,
                              void* d_out, int out_size, void* d_ws, size_t ws_size,
                              hipStream_t stream)
{
    const float* xyz1 = (const float*)d_in[0];
    const float* xyz2 = (const float*)d_in[1];
    float* out = (float*)d_out;

    float* fsum = (float*)d_ws;                       // 24*2*2048 floats
    float* gsum = fsum + (size_t)NPROB * 2 * NPTS;    // 24*2*2048 floats
    unsigned* bars = (unsigned*)(gsum + (size_t)NPROB * 2 * NPTS);

    // barrier state zero + g0 such that K*phi0 = 0 (deterministic per call)
    hipMemsetAsync(bars, 0, (size_t)NPROB * 64 * sizeof(unsigned), stream);
    init_sums<<<(NPROB * 2 * NPTS + 255) / 256, 256, 0, stream>>>(gsum);

    // co-residency-safe grid: clamp to what the runtime will actually co-schedule
    int maxB = 0;
    hipOccupancyMaxActiveBlocksPerMultiprocessor(&maxB, sinkhorn_all, TPB, 0);
    if (maxB < 1) maxB = 1;
    int bpp = (maxB * 256) / NPROB;
    if (bpp > NJOBS) bpp = NJOBS;
    if (bpp < 1) bpp = 1;
    int nblk = NPROB * bpp;

    void* args[] = { (void*)&xyz1, (void*)&xyz2, (void*)&fsum, (void*)&gsum,
                     (void*)&bars, (void*)&bpp };
    hipLaunchCooperativeKernel((void*)sinkhorn_all, dim3(nblk), dim3(TPB),
                               args, 0, stream);

    final_reduce<<<1, TPB, 0, stream>>>(fsum, gsum, out);
}